// Round 19
// baseline (226.280 us; speedup 1.0000x reference)
//
#include <hip/hip_runtime.h>
#include <hip/hip_bf16.h>

typedef __attribute__((ext_vector_type(8))) short short8;
typedef __attribute__((ext_vector_type(4))) float f32x4;
typedef __attribute__((ext_vector_type(4))) unsigned int u32x4;

#define HWPIX 147456   // 384*384
#define NC 64
#define NO 64
#define NM 4
#define EPSV 1e-5f

// f32 pair -> packed bf16x2, round-to-nearest-even (hardware instruction).
static __device__ __forceinline__ unsigned int cvt_pk(float a, float b) {
    unsigned int r;
    asm("v_cvt_pk_bf16_f32 %0, %1, %2" : "=v"(r) : "v"(a), "v"(b));
    return r;
}

// R19: zero-LDS, zero-barrier, VALID register budget (R18 retry).
// Wave = (pixel-group, os-pair): waves {0,1} own pixel-group 0 with os
// {0,1} / {2,3}; waves {2,3} own pixel-group 1.  W regs = 16 short8 = 64
// VGPR (fits; R18's 32 short8 = 128 spilled).  LN computed 2x per pixel
// (redundancy bounded; partner wave's x loads are L1/L2-hot).
// Numerics byte-identical to R17/R18: frag-aligned LN, 1-term xh*Wh,
// sum_m max(z,q) - 4q, nt stores.
__global__ __launch_bounds__(256) void dnm_fused(
    const float* __restrict__ x, const float* __restrict__ Wg,
    const float* __restrict__ qp, const float* __restrict__ gamma,
    const float* __restrict__ beta, float* __restrict__ out)
{
    const int tid = threadIdx.x;
    const int wv  = tid >> 6;
    const int pg  = wv >> 1;         // pixel group 0/1 (128 px each)
    const int op  = wv & 1;          // os pair: {0,1} or {2,3}
    const int ln  = tid & 63;
    const int p16 = ln & 15;         // pixel within subtile / W-frag B-row
    const int g4  = ln >> 4;         // k-chunk group 0..3

    const int bid = blockIdx.x;      // 2304 blocks: 576 strips of 256 px per image
    const int b       = bid / 576;
    const int pixbase = (bid % 576) * 256 + pg * 128;   // wave's 128 px

    const float qv = qp[0];
    const float q4 = 4.0f * qv;

    // ---- W' = gamma .* W -> bf16 (RNE) for THIS wave's 2 o-slices;
    // bias[m][osl] = sum_c beta_c * W[m][o][c], o = (op*2+osl)*16+p16.
    f32x4 gA[2], gB[2], bA[2], bB[2];
#pragma unroll
    for (int ch = 0; ch < 2; ++ch) {
        gA[ch] = *(const f32x4*)(gamma + ch * 32 + g4 * 8);
        gB[ch] = *(const f32x4*)(gamma + ch * 32 + g4 * 8 + 4);
        bA[ch] = *(const f32x4*)(beta  + ch * 32 + g4 * 8);
        bB[ch] = *(const f32x4*)(beta  + ch * 32 + g4 * 8 + 4);
    }
    short8 wh[NM][2][2];             // [m][osl][ch] = 16 short8 = 64 VGPR
    float  bias[NM][2];
#pragma unroll
    for (int m = 0; m < NM; ++m) {
#pragma unroll
        for (int osl = 0; osl < 2; ++osl) {
            const int o = (op * 2 + osl) * 16 + p16;
            float bsum = 0.f;
#pragma unroll
            for (int ch = 0; ch < 2; ++ch) {
                const float* wp = Wg + ((m * NO + o) * NC + ch * 32 + g4 * 8);
                f32x4 a = *(const f32x4*)(wp);
                f32x4 c = *(const f32x4*)(wp + 4);
                float f[8]  = {a[0], a[1], a[2], a[3], c[0], c[1], c[2], c[3]};
                float gg[8] = {gA[ch][0], gA[ch][1], gA[ch][2], gA[ch][3],
                               gB[ch][0], gB[ch][1], gB[ch][2], gB[ch][3]};
                float bb[8] = {bA[ch][0], bA[ch][1], bA[ch][2], bA[ch][3],
                               bB[ch][0], bB[ch][1], bB[ch][2], bB[ch][3]};
                float wq[8];
#pragma unroll
                for (int j = 0; j < 8; ++j) {
                    bsum += bb[j] * f[j];
                    wq[j] = gg[j] * f[j];
                }
                u32x4 hu;
#pragma unroll
                for (int p = 0; p < 4; ++p) hu[p] = cvt_pk(wq[2*p], wq[2*p+1]);
                wh[m][osl][ch] = __builtin_bit_cast(short8, hu);
            }
            bsum += __shfl_xor(bsum, 16);
            bsum += __shfl_xor(bsum, 32);   // full sum over c for this o
            bias[m][osl] = bsum;
        }
    }

    // x base: pixel column p16; channels g4*8.. (frag-aligned, R5-proven)
    const float* xpl = x + (size_t)b * NC * HWPIX + pixbase + p16
                         + (size_t)(g4 * 8) * HWPIX;
    // out base: o-row (op*2)*16+p16 (osl adds 16 rows), pixel g4*4
    float* const outw = out + (size_t)b * NO * HWPIX
                            + (size_t)(op * 32 + p16) * HWPIX + pixbase + g4 * 4;

    // prologue: loads for it=0  (channels {g4*8+j, 32+g4*8+j} of pixel p16)
    float xv[16];
#pragma unroll
    for (int j = 0; j < 8; ++j) {
        xv[j]     = xpl[(size_t)j * HWPIX];
        xv[8 + j] = xpl[(size_t)(32 + j) * HWPIX];
    }

#pragma unroll 1
    for (int it = 0; it < 8; ++it) {
        // ---- LN on prefetched xv (one pixel per lane-column)
        float s1 = 0.f, s2 = 0.f;
#pragma unroll
        for (int i = 0; i < 16; ++i) { s1 += xv[i]; s2 += xv[i] * xv[i]; }
        s1 += __shfl_xor(s1, 16);  s2 += __shfl_xor(s2, 16);
        s1 += __shfl_xor(s1, 32);  s2 += __shfl_xor(s2, 32);
        const float mu  = s1 * (1.f / 64.f);
        const float var = s2 * (1.f / 64.f) - mu * mu;   // biased (torch)
        const float rs  = rsqrtf(var + EPSV);

        // xn -> bf16 A-fragments, in-lane (frag-aligned, R5/R18-proven)
        u32x4 h0, h1;
#pragma unroll
        for (int p = 0; p < 4; ++p) {
            h0[p] = cvt_pk((xv[2*p]   - mu) * rs, (xv[2*p+1] - mu) * rs);
            h1[p] = cvt_pk((xv[8+2*p] - mu) * rs, (xv[9+2*p] - mu) * rs);
        }
        short8 ah[2] = {__builtin_bit_cast(short8, h0), __builtin_bit_cast(short8, h1)};

        // ---- issue next iter's loads (no barrier; fly under MFMA+stores)
        if (it < 7) {
            const float* xp = xpl + (it + 1) * 16;
#pragma unroll
            for (int j = 0; j < 8; ++j) {
                xv[j]     = xp[(size_t)j * HWPIX];
                xv[8 + j] = xp[(size_t)(32 + j) * HWPIX];
            }
        }

        // ---- MFMA: this wave's 16 px x its 32 outputs (2 o-slices)
#pragma unroll 1
        for (int osl = 0; osl < 2; ++osl) {
            f32x4 acc[NM];
#pragma unroll
            for (int m = 0; m < NM; ++m) {
                f32x4 a = {bias[m][osl], bias[m][osl], bias[m][osl], bias[m][osl]};
#pragma unroll
                for (int ch = 0; ch < 2; ++ch) {
                    // 1-term: xh*Wh (R17-proven, absmax 0.15625)
                    a = __builtin_amdgcn_mfma_f32_16x16x32_bf16(ah[ch], wh[m][osl][ch], a, 0, 0, 0);
                }
                acc[m] = a;
            }
            // sum_m relu(z-q) = sum_m max(z,q) - 4q; D: col(p16)=o-local,
            // row(g4*4+rr)=pixel-local (R5/R18-proven store mapping)
            f32x4 v;
#pragma unroll
            for (int rr = 0; rr < 4; ++rr) {
                v[rr] = (fmaxf(acc[0][rr], qv) + fmaxf(acc[1][rr], qv))
                      + (fmaxf(acc[2][rr], qv) + fmaxf(acc[3][rr], qv)) - q4;
            }
            __builtin_nontemporal_store(
                v, (f32x4*)(outw + (size_t)(osl * 16) * HWPIX + it * 16));
        }
    }
}

extern "C" void kernel_launch(void* const* d_in, const int* in_sizes, int n_in,
                              void* d_out, int out_size, void* d_ws, size_t ws_size,
                              hipStream_t stream) {
    const float* x     = (const float*)d_in[0];
    const float* Wg    = (const float*)d_in[1];
    const float* q     = (const float*)d_in[2];
    const float* gamma = (const float*)d_in[3];
    const float* beta  = (const float*)d_in[4];
    float* out = (float*)d_out;

    // 4 images * 576 strips of 256 px = 2304 blocks; 4 independent waves each
    dnm_fused<<<dim3(2304), dim3(256), 0, stream>>>(x, Wg, q, gamma, beta, out);
}

// Round 20
// 72.899 us; speedup vs baseline: 3.1040x; 3.1040x over previous
//
#include <hip/hip_runtime.h>
#include <hip/hip_bf16.h>

typedef __attribute__((ext_vector_type(8))) short short8;
typedef __attribute__((ext_vector_type(4))) float f32x4;
typedef __attribute__((ext_vector_type(4))) unsigned int u32x4;

#define HWPIX 147456   // 384*384
#define NC 64
#define NO 64
#define NM 4
#define EPSV 1e-5f

// f32 pair -> packed bf16x2, round-to-nearest-even (hardware instruction).
static __device__ __forceinline__ unsigned int cvt_pk(float a, float b) {
    unsigned int r;
    asm("v_cvt_pk_bf16_f32 %0, %1, %2" : "=v"(r) : "v"(a), "v"(b));
    return r;
}

// raw barrier: LDS-visibility only, keeps global loads in flight (T4)
#define BAR() do { asm volatile("s_waitcnt lgkmcnt(0)" ::: "memory"); \
                   __builtin_amdgcn_s_barrier();                      \
                   asm volatile("" ::: "memory"); } while (0)

// R17-proven skeleton: LayerNorm -> stacked 1x1 conv -> sum_m relu(z-q).
// A = xn-hi (LDS dbuf, XOR-swizzled), B = gamma*W bf16 (regs), beta folded
// into acc init.  1-term xh*Wh.  Epilogue: sum_m max(z,q) - 4q; nt stores.
// R20: ps loop unrolled + the 4 nt stores deferred and issued BACK-TO-BACK
// so each o-row's 4x64B chunks (256B contiguous) write-combine into full
// HBM lines (R19 showed isolated 64B nt chunks amplify 2x).
__global__ __launch_bounds__(256) void dnm_fused(
    const float* __restrict__ x, const float* __restrict__ Wg,
    const float* __restrict__ qp, const float* __restrict__ gamma,
    const float* __restrict__ beta, float* __restrict__ out)
{
    // per buffer: xn-hi. Row = pixel (64 rows x 128B of bf16[64]),
    // 16B slots swizzled: byte = r*128 + ((slot ^ (r&7))<<4)
    __shared__ __align__(16) unsigned char lds[2][8192];

    const int tid = threadIdx.x;
    const int wv  = tid >> 6;        // wave 0..3 (owns o-slice wv*16..+16)
    const int ln  = tid & 63;
    const int p16 = ln & 15;
    const int g4  = ln >> 4;         // k-chunk group 0..3

    const int bid = blockIdx.x;      // 1152 blocks: 288 strips of 512 px per image
    const int b       = bid / 288;
    const int pixbase = (bid % 288) * 512;

    const float qv = qp[0];
    const float q4 = 4.0f * qv;

    // ---- B operand: W' = gamma .* W -> bf16 (RNE); bias[m] = sum_c beta_c*W
    // lane holds row o = wv*16+p16, k = ch*32 + g4*8 + j
    f32x4 gA[2], gB[2], bA[2], bB[2];
#pragma unroll
    for (int ch = 0; ch < 2; ++ch) {
        gA[ch] = *(const f32x4*)(gamma + ch * 32 + g4 * 8);
        gB[ch] = *(const f32x4*)(gamma + ch * 32 + g4 * 8 + 4);
        bA[ch] = *(const f32x4*)(beta  + ch * 32 + g4 * 8);
        bB[ch] = *(const f32x4*)(beta  + ch * 32 + g4 * 8 + 4);
    }
    short8 wh[NM][2];
    float bias[NM];
#pragma unroll
    for (int m = 0; m < NM; ++m) {
        float bsum = 0.f;
#pragma unroll
        for (int ch = 0; ch < 2; ++ch) {
            const float* wp = Wg + ((m * NO + (wv * 16 + p16)) * NC + ch * 32 + g4 * 8);
            f32x4 a = *(const f32x4*)(wp);
            f32x4 c = *(const f32x4*)(wp + 4);
            float f[8]  = {a[0], a[1], a[2], a[3], c[0], c[1], c[2], c[3]};
            float gg[8] = {gA[ch][0], gA[ch][1], gA[ch][2], gA[ch][3],
                           gB[ch][0], gB[ch][1], gB[ch][2], gB[ch][3]};
            float bb[8] = {bA[ch][0], bA[ch][1], bA[ch][2], bA[ch][3],
                           bB[ch][0], bB[ch][1], bB[ch][2], bB[ch][3]};
            float wq[8];
#pragma unroll
            for (int j = 0; j < 8; ++j) {
                bsum += bb[j] * f[j];
                wq[j] = gg[j] * f[j];
            }
            u32x4 hu;
#pragma unroll
            for (int p = 0; p < 4; ++p) hu[p] = cvt_pk(wq[2*p], wq[2*p+1]);
            wh[m][ch] = __builtin_bit_cast(short8, hu);
        }
        bsum += __shfl_xor(bsum, 16);
        bsum += __shfl_xor(bsum, 32);   // full sum over c for this o
        bias[m] = bsum;
    }

    const float* xpl = x + (size_t)b * NC * HWPIX + pixbase + wv * 16 + p16
                         + (size_t)(g4 * 16) * HWPIX;
    float* const outw = out + (size_t)b * NO * HWPIX
                            + (size_t)(wv * 16 + p16) * HWPIX + pixbase;

    const int r  = wv * 16 + p16;    // LDS row this lane writes
    const int rk = r & 7;

    // prologue: loads for it=0
    float xv[16];
#pragma unroll
    for (int i = 0; i < 16; ++i) xv[i] = xpl[(size_t)i * HWPIX];

#pragma unroll 1
    for (int it = 0; it < 8; ++it) {
        unsigned char* buf = lds[it & 1];

        // ---- LN on prefetched xv (this wave's 16-px subtile, once per pixel)
        {
            float s1 = 0.f, s2 = 0.f;
#pragma unroll
            for (int i = 0; i < 16; ++i) { s1 += xv[i]; s2 += xv[i] * xv[i]; }
            s1 += __shfl_xor(s1, 16);  s2 += __shfl_xor(s2, 16);
            s1 += __shfl_xor(s1, 32);  s2 += __shfl_xor(s2, 32);
            const float mu  = s1 * (1.f / 64.f);
            const float var = s2 * (1.f / 64.f) - mu * mu;   // biased (torch)
            const float rs  = rsqrtf(var + EPSV);
            u32x4 h0, h1;
#pragma unroll
            for (int p = 0; p < 4; ++p) {
                h0[p] = cvt_pk((xv[2*p]     - mu) * rs, (xv[2*p+1] - mu) * rs);
                h1[p] = cvt_pk((xv[8+2*p]   - mu) * rs, (xv[9+2*p] - mu) * rs);
            }
            const int s0 = g4 * 2;
            *(u32x4*)(buf + r * 128 + (((s0    ) ^ rk) << 4)) = h0;
            *(u32x4*)(buf + r * 128 + (((s0 + 1) ^ rk) << 4)) = h1;
        }
        BAR();

        // ---- prefetch next tile's x (in flight across the MFMA phase)
        if (it < 7) {
            const float* xp = xpl + (it + 1) * 64;
#pragma unroll
            for (int i = 0; i < 16; ++i) xv[i] = xp[(size_t)i * HWPIX];
        }

        // ---- MFMA: all 4 pixel-subtiles; stores DEFERRED to a grouped flush
        f32x4 vout[4];
#pragma unroll
        for (int ps = 0; ps < 4; ++ps) {
            const int row = ps * 16 + p16;
            const int rwk = row & 7;
            short8 ah[2];
#pragma unroll
            for (int ch = 0; ch < 2; ++ch) {
                const int slot = ch * 4 + g4;
                ah[ch] = *(const short8*)(buf + row * 128 + ((slot ^ rwk) << 4));
            }
            f32x4 acc[NM];
#pragma unroll
            for (int m = 0; m < NM; ++m) {
                f32x4 a = {bias[m], bias[m], bias[m], bias[m]};
#pragma unroll
                for (int ch = 0; ch < 2; ++ch) {
                    // 1-term: xh*Wh (R17-proven, absmax 0.15625)
                    a = __builtin_amdgcn_mfma_f32_16x16x32_bf16(ah[ch], wh[m][ch], a, 0, 0, 0);
                }
                acc[m] = a;
            }
            // sum_m relu(z-q) = sum_m max(z,q) - 4q (R4-proven)
#pragma unroll
            for (int rr = 0; rr < 4; ++rr) {
                vout[ps][rr] = (fmaxf(acc[0][rr], qv) + fmaxf(acc[1][rr], qv))
                             + (fmaxf(acc[2][rr], qv) + fmaxf(acc[3][rr], qv)) - q4;
            }
        }
        // ---- grouped flush: 4 nt stores back-to-back; per o-row the 4x64B
        // chunks are address-contiguous (256B) -> write-combine to full lines
#pragma unroll
        for (int ps = 0; ps < 4; ++ps) {
            __builtin_nontemporal_store(
                vout[ps], (f32x4*)(outw + it * 64 + ps * 16 + g4 * 4));
        }
        // single barrier per iter: buffer reuse at it+2 is ordered by
        // BAR(it+1), which every wave reaches only after its it-phase reads.
    }
}

extern "C" void kernel_launch(void* const* d_in, const int* in_sizes, int n_in,
                              void* d_out, int out_size, void* d_ws, size_t ws_size,
                              hipStream_t stream) {
    const float* x     = (const float*)d_in[0];
    const float* Wg    = (const float*)d_in[1];
    const float* q     = (const float*)d_in[2];
    const float* gamma = (const float*)d_in[3];
    const float* beta  = (const float*)d_in[4];
    float* out = (float*)d_out;

    // 4 images * 288 strips of 512 px = 1152 blocks (R9 grid)
    dnm_fused<<<dim3(1152), dim3(256), 0, stream>>>(x, Wg, q, gamma, beta, out);
}

// Round 21
// 69.101 us; speedup vs baseline: 3.2746x; 1.0550x over previous
//
#include <hip/hip_runtime.h>
#include <hip/hip_bf16.h>

typedef __attribute__((ext_vector_type(8))) short short8;
typedef __attribute__((ext_vector_type(4))) float f32x4;
typedef __attribute__((ext_vector_type(4))) unsigned int u32x4;

#define HWPIX 147456   // 384*384
#define NC 64
#define NO 64
#define NM 4
#define EPSV 1e-5f

// f32 pair -> packed bf16x2, round-to-nearest-even (hardware instruction).
static __device__ __forceinline__ unsigned int cvt_pk(float a, float b) {
    unsigned int r;
    asm("v_cvt_pk_bf16_f32 %0, %1, %2" : "=v"(r) : "v"(a), "v"(b));
    return r;
}

// async global->LDS, 16B per lane: LDS dest = uniform base + lane*16 (m104)
static __device__ __forceinline__ void gll16(const float* g, unsigned char* l) {
    __builtin_amdgcn_global_load_lds(
        (const __attribute__((address_space(1))) unsigned int*)g,
        (__attribute__((address_space(3))) unsigned int*)l, 16, 0, 0);
}

// Fused LayerNorm -> stacked 1x1 conv -> sum_m relu(z-q).
// R21: x staged via global_load_lds (4 x 1KB-contiguous instrs per wave per
// 64-px tile) into linear [c][px] LDS (dbuf), source pre-swizzled
// (slot = quad ^ (5*(c>>4)&15)) so per-pixel column ds_reads are ~2-way.
// Counted vmcnt (T4: 8 steady, 4 at edges), 2 raw barriers/iter.
// LN / cvt_pk / frag layout / 1-term MFMA / epilogue / nt stores byte-
// identical to R17 (absmax 0.15625 expected exactly).
__global__ __launch_bounds__(256) void dnm_fused(
    const float* __restrict__ x, const float* __restrict__ Wg,
    const float* __restrict__ qp, const float* __restrict__ gamma,
    const float* __restrict__ beta, float* __restrict__ out)
{
    // raw x: [64 ch][16 slots x 16B] = 16KB per buffer, double-buffered.
    __shared__ __align__(16) unsigned char xraw[2][16384];
    // xn frags: 64 rows (pixel) x 128B, slots swizzled ((slot^(r&7))<<4).
    __shared__ __align__(16) unsigned char frag[8192];

    const int tid = threadIdx.x;
    const int wv  = tid >> 6;        // wave 0..3 (owns o-slice wv*16..+16)
    const int ln  = tid & 63;
    const int p16 = ln & 15;
    const int g4  = ln >> 4;         // k-chunk group 0..3

    const int bid = blockIdx.x;      // 1152 blocks: 288 strips of 512 px per image
    const int b       = bid / 288;
    const int pixbase = (bid % 288) * 512;

    const float qv = qp[0];
    const float q4 = 4.0f * qv;

    // ---- B operand: W' = gamma.*W -> bf16 (RNE); bias[m] = sum_c beta_c*W
    // lane holds row o = wv*16+p16, k = ch*32 + g4*8 + j   (R17 verbatim)
    f32x4 gA[2], gB[2], bA[2], bB[2];
#pragma unroll
    for (int ch = 0; ch < 2; ++ch) {
        gA[ch] = *(const f32x4*)(gamma + ch * 32 + g4 * 8);
        gB[ch] = *(const f32x4*)(gamma + ch * 32 + g4 * 8 + 4);
        bA[ch] = *(const f32x4*)(beta  + ch * 32 + g4 * 8);
        bB[ch] = *(const f32x4*)(beta  + ch * 32 + g4 * 8 + 4);
    }
    short8 wh[NM][2];
    float bias[NM];
#pragma unroll
    for (int m = 0; m < NM; ++m) {
        float bsum = 0.f;
#pragma unroll
        for (int ch = 0; ch < 2; ++ch) {
            const float* wp = Wg + ((m * NO + (wv * 16 + p16)) * NC + ch * 32 + g4 * 8);
            f32x4 a = *(const f32x4*)(wp);
            f32x4 c = *(const f32x4*)(wp + 4);
            float f[8]  = {a[0], a[1], a[2], a[3], c[0], c[1], c[2], c[3]};
            float gg[8] = {gA[ch][0], gA[ch][1], gA[ch][2], gA[ch][3],
                           gB[ch][0], gB[ch][1], gB[ch][2], gB[ch][3]};
            float bb[8] = {bA[ch][0], bA[ch][1], bA[ch][2], bA[ch][3],
                           bB[ch][0], bB[ch][1], bB[ch][2], bB[ch][3]};
            float wq[8];
#pragma unroll
            for (int j = 0; j < 8; ++j) {
                bsum += bb[j] * f[j];
                wq[j] = gg[j] * f[j];
            }
            u32x4 hu;
#pragma unroll
            for (int p = 0; p < 4; ++p) hu[p] = cvt_pk(wq[2*p], wq[2*p+1]);
            wh[m][ch] = __builtin_bit_cast(short8, hu);
        }
        bsum += __shfl_xor(bsum, 16);
        bsum += __shfl_xor(bsum, 32);   // full sum over c for this o
        bias[m] = bsum;
    }

    // ---- staging setup: wave wv stages channels wv*16..wv*16+15.
    // lane l -> (c_local = l>>4, dest slot = l&15); source quad pre-swizzled.
    const int kw   = (5 * wv) & 15;
    const int cl   = ln >> 4;
    const int qsrc = (ln & 15) ^ kw;     // pixel quad this lane fetches
    const float* gsrc[4];
#pragma unroll
    for (int i = 0; i < 4; ++i)
        gsrc[i] = x + (size_t)b * NC * HWPIX
                    + (size_t)(wv * 16 + i * 4 + cl) * HWPIX
                    + pixbase + qsrc * 4;

    float* const outw = out + (size_t)b * NO * HWPIX
                            + (size_t)(wv * 16 + p16) * HWPIX + pixbase;

    const int r  = wv * 16 + p16;    // frag-LDS row this lane writes
    const int rk = r & 7;

    auto STAGE = [&](int t, int bsel) {
#pragma unroll
        for (int i = 0; i < 4; ++i)
            gll16(gsrc[i] + t * 64, &xraw[bsel][(wv * 16 + i * 4) * 256]);
    };

    // prologue: stage tile 0
    STAGE(0, 0);

#pragma unroll 1
    for (int t = 0; t < 8; ++t) {
        const unsigned char* braw = xraw[t & 1];
        if (t < 7) STAGE(t + 1, (t + 1) & 1);

        // counted vmcnt: stage(t) is the oldest 4 of <=12 outstanding
        // (stores(t-1) 4 + stage(t+1) 4); edges have no stage(t+1).
        if (t == 0 || t == 7) asm volatile("s_waitcnt vmcnt(4)" ::: "memory");
        else                  asm volatile("s_waitcnt vmcnt(8)" ::: "memory");
        __builtin_amdgcn_s_barrier();
        asm volatile("" ::: "memory");

        // ---- LN phase: lane (g4,p16) reads channels g4*16+ic of pixel
        // wv*16+p16 from the staged tile (slot = quad ^ (5*g4 & 15)).
        {
            const int s = ((wv * 4 + (p16 >> 2)) ^ ((5 * g4) & 15));
            const unsigned char* rbase = braw + (g4 * 16) * 256 + s * 16 + (p16 & 3) * 4;
            float xv[16];
#pragma unroll
            for (int ic = 0; ic < 16; ++ic)
                xv[ic] = *(const float*)(rbase + ic * 256);

            float s1 = 0.f, s2 = 0.f;
#pragma unroll
            for (int i = 0; i < 16; ++i) { s1 += xv[i]; s2 += xv[i] * xv[i]; }
            s1 += __shfl_xor(s1, 16);  s2 += __shfl_xor(s2, 16);
            s1 += __shfl_xor(s1, 32);  s2 += __shfl_xor(s2, 32);
            const float mu  = s1 * (1.f / 64.f);
            const float var = s2 * (1.f / 64.f) - mu * mu;   // biased (torch)
            const float rs  = rsqrtf(var + EPSV);
            u32x4 h0, h1;
#pragma unroll
            for (int p = 0; p < 4; ++p) {
                h0[p] = cvt_pk((xv[2*p]     - mu) * rs, (xv[2*p+1] - mu) * rs);
                h1[p] = cvt_pk((xv[8+2*p]   - mu) * rs, (xv[9+2*p] - mu) * rs);
            }
            const int s0 = g4 * 2;
            *(u32x4*)(frag + r * 128 + (((s0    ) ^ rk) << 4)) = h0;
            *(u32x4*)(frag + r * 128 + (((s0 + 1) ^ rk) << 4)) = h1;
        }
        asm volatile("s_waitcnt lgkmcnt(0)" ::: "memory");
        __builtin_amdgcn_s_barrier();
        asm volatile("" ::: "memory");

        // ---- MFMA: wave covers its o-slice for all 4 pixel-subtiles
#pragma unroll 1
        for (int ps = 0; ps < 4; ++ps) {
            const int row = ps * 16 + p16;
            const int rwk = row & 7;
            short8 ah[2];
#pragma unroll
            for (int ch = 0; ch < 2; ++ch) {
                const int slot = ch * 4 + g4;
                ah[ch] = *(const short8*)(frag + row * 128 + ((slot ^ rwk) << 4));
            }
            f32x4 acc[NM];
#pragma unroll
            for (int m = 0; m < NM; ++m) {
                f32x4 a = {bias[m], bias[m], bias[m], bias[m]};
#pragma unroll
                for (int ch = 0; ch < 2; ++ch) {
                    // 1-term: xh*Wh (R17-proven, absmax 0.15625)
                    a = __builtin_amdgcn_mfma_f32_16x16x32_bf16(ah[ch], wh[m][ch], a, 0, 0, 0);
                }
                acc[m] = a;
            }
            // sum_m relu(z-q) = sum_m max(z,q) - 4q (R4-proven);
            // D: col(p16)=o-local, row(g4*4+rr)=pixel-local
            f32x4 v;
#pragma unroll
            for (int rr = 0; rr < 4; ++rr) {
                v[rr] = (fmaxf(acc[0][rr], qv) + fmaxf(acc[1][rr], qv))
                      + (fmaxf(acc[2][rr], qv) + fmaxf(acc[3][rr], qv)) - q4;
            }
            __builtin_nontemporal_store(
                v, (f32x4*)(outw + t * 64 + ps * 16 + g4 * 4));
        }
        asm volatile("" ::: "memory");   // pin store/stage program order
        // xraw dbuf: stage(t+2) (issued next iter, after barrier 1) cannot
        // race this iter's reads; frag single-buffer ordered by barrier 1.
    }
}

extern "C" void kernel_launch(void* const* d_in, const int* in_sizes, int n_in,
                              void* d_out, int out_size, void* d_ws, size_t ws_size,
                              hipStream_t stream) {
    const float* x     = (const float*)d_in[0];
    const float* Wg    = (const float*)d_in[1];
    const float* q     = (const float*)d_in[2];
    const float* gamma = (const float*)d_in[3];
    const float* beta  = (const float*)d_in[4];
    float* out = (float*)d_out;

    // 4 images * 288 strips of 512 px = 1152 blocks
    dnm_fused<<<dim3(1152), dim3(256), 0, stream>>>(x, Wg, q, gamma, beta, out);
}